// Round 4
// baseline (50.612 us; speedup 1.0000x reference)
//
#include <hip/hip_runtime.h>

// DiceLoss: input (B=16, C=4, H=512, W=512) f32, target (B,H,W) int32.
// pred = argmax_c input; per class c: pp=#pred==c, tt=#tgt==c, ii=#(pred==c & tgt==c).
// loss = mean_c (1 - (2*ii+eps)/(pp+tt+eps)).
// Single fused dispatch: grid-wide counting + last-block-ticket finalization.

static constexpr int kHW     = 512 * 512;       // 262144
static constexpr int kC      = 4;
static constexpr int kNPix   = 16 * kHW;        // 4194304
static constexpr int kNVec   = kNPix / 4;       // 1048576 quads
static constexpr int kBlocks  = 1024;
static constexpr int kThreads = 256;
static constexpr int kT       = kBlocks * kThreads;  // 262144 threads
static constexpr int kQT      = kNVec / kT;          // 4 quads/thread (exact)
static constexpr float kEps = 1e-6f;

__device__ __forceinline__ void quad_count(
    const float4& c0, const float4& c1, const float4& c2, const float4& c3,
    const int4& t4, unsigned int& pp, unsigned int& tt, unsigned int& ii)
{
    const float a0[4] = {c0.x, c0.y, c0.z, c0.w};
    const float a1[4] = {c1.x, c1.y, c1.z, c1.w};
    const float a2[4] = {c2.x, c2.y, c2.z, c2.w};
    const float a3[4] = {c3.x, c3.y, c3.z, c3.w};
    const int   tv[4] = {t4.x, t4.y, t4.z, t4.w};
#pragma unroll
    for (int j = 0; j < 4; ++j) {
        int pred = 0; float bv = a0[j];
        if (a1[j] > bv) { bv = a1[j]; pred = 1; }
        if (a2[j] > bv) { bv = a2[j]; pred = 2; }
        if (a3[j] > bv) { bv = a3[j]; pred = 3; }
        const int t = tv[j];
        pp += 1u << (pred << 3);
        tt += 1u << (t << 3);
        ii += (unsigned int)(pred == t) << (t << 3);
    }
}

// ws layout: partial[12 * kBlocks] (c-major), then ticket (1 uint).
__global__ __launch_bounds__(kThreads) void dice_fused_kernel(
    const float* __restrict__ in, const int* __restrict__ tgt,
    unsigned int* __restrict__ partial, unsigned int* __restrict__ ticket,
    float* __restrict__ out)
{
    const int tid = blockIdx.x * kThreads + threadIdx.x;

    unsigned int pp = 0, tt = 0, ii = 0;   // byte-packed; max 16 pixels/thread per field

#pragma unroll
    for (int it = 0; it < kQT; it += 2) {
        const int v0 = tid + it * kT;
        const int v1 = tid + (it + 1) * kT;
        const int p0 = v0 << 2, p1 = v1 << 2;
        const float* baseA = in + (size_t)(p0 >> 18) * (kC * kHW) + (p0 & (kHW - 1));
        const float* baseB = in + (size_t)(p1 >> 18) * (kC * kHW) + (p1 & (kHW - 1));

        // issue all 10 loads before consuming any
        const float4 A0 = *(const float4*)(baseA);
        const float4 A1 = *(const float4*)(baseA + kHW);
        const float4 A2 = *(const float4*)(baseA + 2 * kHW);
        const float4 A3 = *(const float4*)(baseA + 3 * kHW);
        const int4   TA = *(const int4*)(tgt + p0);
        const float4 B0 = *(const float4*)(baseB);
        const float4 B1 = *(const float4*)(baseB + kHW);
        const float4 B2 = *(const float4*)(baseB + 2 * kHW);
        const float4 B3 = *(const float4*)(baseB + 3 * kHW);
        const int4   TB = *(const int4*)(tgt + p1);

        quad_count(A0, A1, A2, A3, TA, pp, tt, ii);
        quad_count(B0, B1, B2, B3, TB, pp, tt, ii);
    }

    // packed butterfly over 8 lanes (fields reach 16*8=128 < 256: no overflow)
#pragma unroll
    for (int o = 1; o <= 4; o <<= 1) {
        pp += __shfl_xor(pp, o, 64);
        tt += __shfl_xor(tt, o, 64);
        ii += __shfl_xor(ii, o, 64);
    }

    // unpack, finish wave reduction at offsets 8/16/32
    unsigned int loc[12];
#pragma unroll
    for (int c = 0; c < 4; ++c) {
        loc[c]     = (pp >> (c * 8)) & 0xFF;
        loc[4 + c] = (tt >> (c * 8)) & 0xFF;
        loc[8 + c] = (ii >> (c * 8)) & 0xFF;
    }
#pragma unroll
    for (int i = 0; i < 12; ++i) {
        loc[i] += __shfl_xor(loc[i], 8, 64);
        loc[i] += __shfl_xor(loc[i], 16, 64);
        loc[i] += __shfl_xor(loc[i], 32, 64);
    }

    // block reduction across 4 waves
    __shared__ unsigned int s[4][12];
    __shared__ bool s_last;
    const int wave = threadIdx.x >> 6;
    if ((threadIdx.x & 63) == 0) {
#pragma unroll
        for (int i = 0; i < 12; ++i) s[wave][i] = loc[i];
    }
    if (threadIdx.x == 0) s_last = false;
    __syncthreads();

    // publish partials at agent scope (bypass non-coherent per-XCD L2)
    if (threadIdx.x < 12) {
        const unsigned int sum = s[0][threadIdx.x] + s[1][threadIdx.x]
                               + s[2][threadIdx.x] + s[3][threadIdx.x];
        __hip_atomic_store(&partial[threadIdx.x * kBlocks + blockIdx.x], sum,
                           __ATOMIC_RELAXED, __HIP_MEMORY_SCOPE_AGENT);
    }
    __syncthreads();

    // ticket: wrap-robust last-block detection.
    // Start state is either 0xAAAAAAAA (harness ws poison) or kBlocks-1 (left by a
    // previous complete call) - both >= kBlocks-1, so the first atomicInc wraps to 0
    // and the block observing old == kBlocks-2 is provably the 1024th arrival.
    if (threadIdx.x == 0) {
        __threadfence();                                    // release partials
        const unsigned int old = atomicInc(ticket, kBlocks - 1);
        if (old == kBlocks - 2) {
            __threadfence();                                // acquire
            s_last = true;
        }
    }
    __syncthreads();
    if (!s_last) return;

    // ---- last block: reduce 12 x kBlocks partials and finalize ----
    const int t = threadIdx.x;
    unsigned int acc[12];
#pragma unroll
    for (int i = 0; i < 12; ++i) acc[i] = 0;
#pragma unroll
    for (int k = 0; k < kBlocks / kThreads; ++k) {
#pragma unroll
        for (int c = 0; c < 12; ++c)
            acc[c] += __hip_atomic_load(&partial[c * kBlocks + k * kThreads + t],
                                        __ATOMIC_RELAXED, __HIP_MEMORY_SCOPE_AGENT);
    }
#pragma unroll
    for (int i = 0; i < 12; ++i) {
#pragma unroll
        for (int o = 1; o <= 32; o <<= 1) acc[i] += __shfl_xor(acc[i], o, 64);
    }

    __shared__ unsigned int f[4][12];
    if ((t & 63) == 0) {
#pragma unroll
        for (int i = 0; i < 12; ++i) f[wave][i] = acc[i];
    }
    __syncthreads();

    if (t == 0) {
        float loss = 0.0f;
#pragma unroll
        for (int c = 0; c < kC; ++c) {
            const float ppc = (float)(f[0][c] + f[1][c] + f[2][c] + f[3][c]);
            const float ttc = (float)(f[0][4+c] + f[1][4+c] + f[2][4+c] + f[3][4+c]);
            const float iic = (float)(f[0][8+c] + f[1][8+c] + f[2][8+c] + f[3][8+c]);
            loss += 1.0f - (2.0f * iic + kEps) / (ppc + ttc + kEps);
        }
        out[0] = loss * 0.25f;
    }
}

extern "C" void kernel_launch(void* const* d_in, const int* in_sizes, int n_in,
                              void* d_out, int out_size, void* d_ws, size_t ws_size,
                              hipStream_t stream) {
    const float* in  = (const float*)d_in[0];
    const int*   tgt = (const int*)d_in[1];
    float* out = (float*)d_out;
    unsigned int* partial = (unsigned int*)d_ws;          // 12 * kBlocks uints = 48 KiB
    unsigned int* ticket  = partial + 12 * kBlocks;       // 1 uint

    dice_fused_kernel<<<kBlocks, kThreads, 0, stream>>>(in, tgt, partial, ticket, out);
}

// Round 5
// 22.289 us; speedup vs baseline: 2.2707x; 2.2707x over previous
//
#include <hip/hip_runtime.h>

// DiceLoss: input (B=16, C=4, H=512, W=512) f32, target (B,H,W) int32.
// pred = argmax_c input; per class c: pp=#pred==c, tt=#tgt==c, ii=#(pred==c & tgt==c).
// loss = mean_c (1 - (2*ii+eps)/(pp+tt+eps)).
//
// Two dispatches (fused single-dispatch variant regressed: same-address ticket
// atomics + agent fences + VGPR starvation; see R4 post-mortem).
// __launch_bounds__(256, 4): min 4 waves/EU -> VGPR cap 128, enough to keep a
// 10-load batch (40 VGPRs of data) in flight. R4's compile chose 36 VGPRs and
// serialized the loads -> 65us while latency-bound on L3-resident data.

static constexpr int kHW     = 512 * 512;       // 262144
static constexpr int kC      = 4;
static constexpr int kNPix   = 16 * kHW;        // 4194304
static constexpr int kNVec   = kNPix / 4;       // 1048576 quads
static constexpr int kBlocks  = 1024;
static constexpr int kThreads = 256;
static constexpr int kT       = kBlocks * kThreads;  // 262144 threads
static constexpr int kQT      = kNVec / kT;          // 4 quads/thread (exact)
static constexpr float kEps = 1e-6f;

__device__ __forceinline__ void quad_count(
    const float4& c0, const float4& c1, const float4& c2, const float4& c3,
    const int4& t4, unsigned int& pp, unsigned int& tt, unsigned int& ii)
{
    const float a0[4] = {c0.x, c0.y, c0.z, c0.w};
    const float a1[4] = {c1.x, c1.y, c1.z, c1.w};
    const float a2[4] = {c2.x, c2.y, c2.z, c2.w};
    const float a3[4] = {c3.x, c3.y, c3.z, c3.w};
    const int   tv[4] = {t4.x, t4.y, t4.z, t4.w};
#pragma unroll
    for (int j = 0; j < 4; ++j) {
        int pred = 0; float bv = a0[j];
        if (a1[j] > bv) { bv = a1[j]; pred = 1; }
        if (a2[j] > bv) { bv = a2[j]; pred = 2; }
        if (a3[j] > bv) { bv = a3[j]; pred = 3; }
        const int t = tv[j];
        pp += 1u << (pred << 3);
        tt += 1u << (t << 3);
        ii += (unsigned int)(pred == t) << (t << 3);
    }
}

// partials layout: partial[c * kBlocks + blk], c in [0,12)
__global__ __launch_bounds__(kThreads, 4) void dice_count_kernel(
    const float* __restrict__ in, const int* __restrict__ tgt,
    unsigned int* __restrict__ partial)
{
    const int tid = blockIdx.x * kThreads + threadIdx.x;

    unsigned int pp = 0, tt = 0, ii = 0;   // byte-packed; max 16 pixels/thread per field

#pragma unroll
    for (int it = 0; it < kQT; it += 2) {
        const int v0 = tid + it * kT;
        const int v1 = tid + (it + 1) * kT;
        const int p0 = v0 << 2, p1 = v1 << 2;
        const float* baseA = in + (size_t)(p0 >> 18) * (kC * kHW) + (p0 & (kHW - 1));
        const float* baseB = in + (size_t)(p1 >> 18) * (kC * kHW) + (p1 & (kHW - 1));

        // issue all 10 loads before consuming any (needs ~40 data VGPRs)
        const float4 A0 = *(const float4*)(baseA);
        const float4 A1 = *(const float4*)(baseA + kHW);
        const float4 A2 = *(const float4*)(baseA + 2 * kHW);
        const float4 A3 = *(const float4*)(baseA + 3 * kHW);
        const int4   TA = *(const int4*)(tgt + p0);
        const float4 B0 = *(const float4*)(baseB);
        const float4 B1 = *(const float4*)(baseB + kHW);
        const float4 B2 = *(const float4*)(baseB + 2 * kHW);
        const float4 B3 = *(const float4*)(baseB + 3 * kHW);
        const int4   TB = *(const int4*)(tgt + p1);

        quad_count(A0, A1, A2, A3, TA, pp, tt, ii);
        quad_count(B0, B1, B2, B3, TB, pp, tt, ii);
    }

    // packed butterfly over 8 lanes (fields reach 16*8=128 < 256: no overflow)
#pragma unroll
    for (int o = 1; o <= 4; o <<= 1) {
        pp += __shfl_xor(pp, o, 64);
        tt += __shfl_xor(tt, o, 64);
        ii += __shfl_xor(ii, o, 64);
    }

    // unpack, finish wave reduction at offsets 8/16/32
    unsigned int loc[12];
#pragma unroll
    for (int c = 0; c < 4; ++c) {
        loc[c]     = (pp >> (c * 8)) & 0xFF;
        loc[4 + c] = (tt >> (c * 8)) & 0xFF;
        loc[8 + c] = (ii >> (c * 8)) & 0xFF;
    }
#pragma unroll
    for (int i = 0; i < 12; ++i) {
        loc[i] += __shfl_xor(loc[i], 8, 64);
        loc[i] += __shfl_xor(loc[i], 16, 64);
        loc[i] += __shfl_xor(loc[i], 32, 64);
    }

    // block reduction across 4 waves
    __shared__ unsigned int s[4][12];
    const int wave = threadIdx.x >> 6;
    if ((threadIdx.x & 63) == 0) {
#pragma unroll
        for (int i = 0; i < 12; ++i) s[wave][i] = loc[i];
    }
    __syncthreads();
    if (threadIdx.x < 12) {
        partial[threadIdx.x * kBlocks + blockIdx.x] =
            s[0][threadIdx.x] + s[1][threadIdx.x] + s[2][threadIdx.x] + s[3][threadIdx.x];
    }
}

__global__ __launch_bounds__(256, 4) void dice_final_kernel(
    const unsigned int* __restrict__ partial, float* __restrict__ out)
{
    const int t = threadIdx.x;
    unsigned int loc[12];
#pragma unroll
    for (int i = 0; i < 12; ++i) loc[i] = 0;

    // k outer / c inner: all 48 loads independent -> deep MLP, coalesced
#pragma unroll
    for (int k = 0; k < kBlocks / 256; ++k) {
#pragma unroll
        for (int c = 0; c < 12; ++c)
            loc[c] += partial[c * kBlocks + k * 256 + t];
    }

#pragma unroll
    for (int i = 0; i < 12; ++i) {
#pragma unroll
        for (int o = 1; o <= 32; o <<= 1) loc[i] += __shfl_xor(loc[i], o, 64);
    }

    __shared__ unsigned int s[4][12];
    const int wave = t >> 6;
    if ((t & 63) == 0) {
#pragma unroll
        for (int i = 0; i < 12; ++i) s[wave][i] = loc[i];
    }
    __syncthreads();

    if (t == 0) {
        float loss = 0.0f;
#pragma unroll
        for (int c = 0; c < kC; ++c) {
            const float ppc = (float)(s[0][c] + s[1][c] + s[2][c] + s[3][c]);
            const float ttc = (float)(s[0][4+c] + s[1][4+c] + s[2][4+c] + s[3][4+c]);
            const float iic = (float)(s[0][8+c] + s[1][8+c] + s[2][8+c] + s[3][8+c]);
            loss += 1.0f - (2.0f * iic + kEps) / (ppc + ttc + kEps);
        }
        out[0] = loss * 0.25f;
    }
}

extern "C" void kernel_launch(void* const* d_in, const int* in_sizes, int n_in,
                              void* d_out, int out_size, void* d_ws, size_t ws_size,
                              hipStream_t stream) {
    const float* in  = (const float*)d_in[0];
    const int*   tgt = (const int*)d_in[1];
    float* out = (float*)d_out;
    unsigned int* partial = (unsigned int*)d_ws;  // 12 * kBlocks uints = 48 KiB

    dice_count_kernel<<<kBlocks, kThreads, 0, stream>>>(in, tgt, partial);
    dice_final_kernel<<<1, 256, 0, stream>>>(partial, out);
}

// Round 6
// 21.794 us; speedup vs baseline: 2.3223x; 1.0227x over previous
//
#include <hip/hip_runtime.h>

// DiceLoss: input (B=16, C=4, H=512, W=512) f32, target (B,H,W) int32.
// pred = argmax_c input; per class c: pp=#pred==c, tt=#tgt==c, ii=#(pred==c & tgt==c).
// loss = mean_c (1 - (2*ii+eps)/(pp+tt+eps)).
//
// R6: inputs are L3-resident across graph replays (R4 profile: steady-state
// FETCH ~0.4MB), so the count kernel is latency-bound, not BW-bound. Single
// 20-load batch per thread (4 quads) -> 80 outstanding loads/SIMD at
// unchanged occupancy (4 waves/SIMD, VGPR cap 128 via launch_bounds(256,4)).

static constexpr int kHW     = 512 * 512;       // 262144
static constexpr int kC      = 4;
static constexpr int kNPix   = 16 * kHW;        // 4194304
static constexpr int kNVec   = kNPix / 4;       // 1048576 quads
static constexpr int kBlocks  = 1024;
static constexpr int kThreads = 256;
static constexpr int kT       = kBlocks * kThreads;  // 262144 threads = 2^18
static constexpr float kEps = 1e-6f;

__device__ __forceinline__ void quad_count(
    const float4& c0, const float4& c1, const float4& c2, const float4& c3,
    const int4& t4, unsigned int& pp, unsigned int& tt, unsigned int& ii)
{
    const float a0[4] = {c0.x, c0.y, c0.z, c0.w};
    const float a1[4] = {c1.x, c1.y, c1.z, c1.w};
    const float a2[4] = {c2.x, c2.y, c2.z, c2.w};
    const float a3[4] = {c3.x, c3.y, c3.z, c3.w};
    const int   tv[4] = {t4.x, t4.y, t4.z, t4.w};
#pragma unroll
    for (int j = 0; j < 4; ++j) {
        int pred = 0; float bv = a0[j];
        if (a1[j] > bv) { bv = a1[j]; pred = 1; }
        if (a2[j] > bv) { bv = a2[j]; pred = 2; }
        if (a3[j] > bv) { bv = a3[j]; pred = 3; }
        const int t = tv[j];
        pp += 1u << (pred << 3);
        tt += 1u << (t << 3);
        ii += (unsigned int)(pred == t) << (t << 3);
    }
}

// partials layout: partial[c * kBlocks + blk], c in [0,12)
__global__ __launch_bounds__(kThreads, 4) void dice_count_kernel(
    const float* __restrict__ in, const int* __restrict__ tgt,
    unsigned int* __restrict__ partial)
{
    const int tid = blockIdx.x * kThreads + threadIdx.x;

    // quad i covers pixel p_i = tid*4 + i*2^20: same hw for all i, b = b0 + 4i.
    const int p0 = tid << 2;
    const int b0 = p0 >> 18;
    const int hw = p0 & (kHW - 1);
    const float* baseA = in + (size_t)b0 * (kC * kHW) + hw;   // batches b0, b0+4, b0+8, b0+12
    const float* baseB = baseA + (size_t)4 * kC * kHW;
    const float* baseC = baseB + (size_t)4 * kC * kHW;
    const float* baseD = baseC + (size_t)4 * kC * kHW;

    // single batch: all 20 loads issued before any consumption (~80 data VGPRs)
    const float4 A0 = *(const float4*)(baseA);
    const float4 A1 = *(const float4*)(baseA + kHW);
    const float4 A2 = *(const float4*)(baseA + 2 * kHW);
    const float4 A3 = *(const float4*)(baseA + 3 * kHW);
    const float4 B0 = *(const float4*)(baseB);
    const float4 B1 = *(const float4*)(baseB + kHW);
    const float4 B2 = *(const float4*)(baseB + 2 * kHW);
    const float4 B3 = *(const float4*)(baseB + 3 * kHW);
    const float4 C0 = *(const float4*)(baseC);
    const float4 C1 = *(const float4*)(baseC + kHW);
    const float4 C2 = *(const float4*)(baseC + 2 * kHW);
    const float4 C3 = *(const float4*)(baseC + 3 * kHW);
    const float4 D0 = *(const float4*)(baseD);
    const float4 D1 = *(const float4*)(baseD + kHW);
    const float4 D2 = *(const float4*)(baseD + 2 * kHW);
    const float4 D3 = *(const float4*)(baseD + 3 * kHW);
    const int4   TA = *(const int4*)(tgt + p0);
    const int4   TB = *(const int4*)(tgt + p0 + (1 << 20));
    const int4   TC = *(const int4*)(tgt + p0 + (2 << 20));
    const int4   TD = *(const int4*)(tgt + p0 + (3 << 20));

    unsigned int pp = 0, tt = 0, ii = 0;   // byte-packed; 16 pixels/thread per field
    quad_count(A0, A1, A2, A3, TA, pp, tt, ii);
    quad_count(B0, B1, B2, B3, TB, pp, tt, ii);
    quad_count(C0, C1, C2, C3, TC, pp, tt, ii);
    quad_count(D0, D1, D2, D3, TD, pp, tt, ii);

    // packed butterfly over 8 lanes (fields reach 16*8=128 < 256: no overflow)
#pragma unroll
    for (int o = 1; o <= 4; o <<= 1) {
        pp += __shfl_xor(pp, o, 64);
        tt += __shfl_xor(tt, o, 64);
        ii += __shfl_xor(ii, o, 64);
    }

    // unpack, finish wave reduction at offsets 8/16/32
    unsigned int loc[12];
#pragma unroll
    for (int c = 0; c < 4; ++c) {
        loc[c]     = (pp >> (c * 8)) & 0xFF;
        loc[4 + c] = (tt >> (c * 8)) & 0xFF;
        loc[8 + c] = (ii >> (c * 8)) & 0xFF;
    }
#pragma unroll
    for (int i = 0; i < 12; ++i) {
        loc[i] += __shfl_xor(loc[i], 8, 64);
        loc[i] += __shfl_xor(loc[i], 16, 64);
        loc[i] += __shfl_xor(loc[i], 32, 64);
    }

    // block reduction across 4 waves
    __shared__ unsigned int s[4][12];
    const int wave = threadIdx.x >> 6;
    if ((threadIdx.x & 63) == 0) {
#pragma unroll
        for (int i = 0; i < 12; ++i) s[wave][i] = loc[i];
    }
    __syncthreads();
    if (threadIdx.x < 12) {
        partial[threadIdx.x * kBlocks + blockIdx.x] =
            s[0][threadIdx.x] + s[1][threadIdx.x] + s[2][threadIdx.x] + s[3][threadIdx.x];
    }
}

__global__ __launch_bounds__(256, 4) void dice_final_kernel(
    const unsigned int* __restrict__ partial, float* __restrict__ out)
{
    const int t = threadIdx.x;
    unsigned int loc[12];

    // one uint4 per class per thread: 12 independent coalesced 16B loads,
    // 256 threads x 4 = 1024 partials per class (exact)
#pragma unroll
    for (int c = 0; c < 12; ++c) {
        const uint4 u = *(const uint4*)(partial + c * kBlocks + t * 4);
        loc[c] = u.x + u.y + u.z + u.w;
    }

#pragma unroll
    for (int i = 0; i < 12; ++i) {
#pragma unroll
        for (int o = 1; o <= 32; o <<= 1) loc[i] += __shfl_xor(loc[i], o, 64);
    }

    __shared__ unsigned int s[4][12];
    const int wave = t >> 6;
    if ((t & 63) == 0) {
#pragma unroll
        for (int i = 0; i < 12; ++i) s[wave][i] = loc[i];
    }
    __syncthreads();

    if (t == 0) {
        float loss = 0.0f;
#pragma unroll
        for (int c = 0; c < kC; ++c) {
            const float ppc = (float)(s[0][c] + s[1][c] + s[2][c] + s[3][c]);
            const float ttc = (float)(s[0][4+c] + s[1][4+c] + s[2][4+c] + s[3][4+c]);
            const float iic = (float)(s[0][8+c] + s[1][8+c] + s[2][8+c] + s[3][8+c]);
            loss += 1.0f - (2.0f * iic + kEps) / (ppc + ttc + kEps);
        }
        out[0] = loss * 0.25f;
    }
}

extern "C" void kernel_launch(void* const* d_in, const int* in_sizes, int n_in,
                              void* d_out, int out_size, void* d_ws, size_t ws_size,
                              hipStream_t stream) {
    const float* in  = (const float*)d_in[0];
    const int*   tgt = (const int*)d_in[1];
    float* out = (float*)d_out;
    unsigned int* partial = (unsigned int*)d_ws;  // 12 * kBlocks uints = 48 KiB

    dice_count_kernel<<<kBlocks, kThreads, 0, stream>>>(in, tgt, partial);
    dice_final_kernel<<<1, 256, 0, stream>>>(partial, out);
}